// Round 1
// baseline (168.112 us; speedup 1.0000x reference)
//
#include <hip/hip_runtime.h>
#include <hip/hip_bf16.h>

// ---- problem constants ----
constexpr int BATCH = 256;          // B
constexpr int MTOK  = 128;          // tokens per text
constexpr int DDIM  = 768;          // embedding dim
constexpr int NV    = BATCH * DDIM; // v elems (= Vq elems)
constexpr float INV_TEMP = 1.0f / 0.07f;

typedef __bf16 bf16;
typedef __bf16 bf16x8 __attribute__((ext_vector_type(8)));
typedef float  f32x4  __attribute__((ext_vector_type(4)));

// ============================================================
// Kernel 0: pack V fp32 -> bf16 in MFMA A-fragment layout.
// Also zeroes the CE arrival counter (ws is poisoned each reset).
// ============================================================
__global__ __launch_bounds__(256) void pack_v_kernel(
        const float* __restrict__ V, bf16x8* __restrict__ Vq,
        unsigned int* __restrict__ counter) {
    if (blockIdx.x == 0 && threadIdx.x == 0) *counter = 0u;
    int c = blockIdx.x * 256 + threadIdx.x;        // 24576 chunks
    int lane = c & 63, fs = c >> 6;
    int ks = fs % 24, g = fs / 24;
    int l15 = lane & 15, quad = lane >> 4;
    const float* src = V + (size_t)(g * 16 + l15) * DDIM + ks * 32 + quad * 8;
    float4 f0 = *(const float4*)(src);
    float4 f1 = *(const float4*)(src + 4);
    bf16x8 o;
    o[0] = (bf16)f0.x; o[1] = (bf16)f0.y; o[2] = (bf16)f0.z; o[3] = (bf16)f0.w;
    o[4] = (bf16)f1.x; o[5] = (bf16)f1.y; o[6] = (bf16)f1.z; o[7] = (bf16)f1.w;
    Vq[c] = o;
}

// ============================================================
// Kernel 1 (v8): block (j, nh) -> M=256 x N=64 tokens.
// BK=128 per iteration (2 x 64-k slabs), 6 iters -> 6 barrier drains
// instead of 12 (hipcc emits vmcnt(0) before every s_barrier; each
// drain exposes HBM latency once, so halving barriers halves stalls).
// A: direct coalesced frag loads from L2-resident Vq, depth-2 h-step
//    prefetch. B: fp32 -> regs -> bf16 -> LDS, double-buffered 2x16KB,
//    ONE barrier per iter. Grid 512, 256 thr -> 2 blocks/CU.
// ============================================================
__global__ __launch_bounds__(256, 2) void gemm_max_kernel(
        const bf16*  __restrict__ Vq,  // packed A frags
        const float* __restrict__ T,   // [32768][768] fp32
        float* __restrict__ Sp) {      // [2][256][256]  Sp[nh][j][i]
    // B buf: 2 slabs x (2 khalf x 64 rows x 64 B) = 16384 B; two bufs.
    __shared__ char  ldsB[2 * 16384];
    __shared__ float smax[256];

    const int jt   = blockIdx.x >> 1;   // text j
    const int nh   = blockIdx.x & 1;    // token half (64 tokens)
    const int tid  = threadIdx.x;
    const int w    = tid >> 6;          // wave 0..3 -> M stripe of 64
    const int lane = tid & 63;
    const int quad = lane >> 4;
    const int l15  = lane & 15;

    // --- A frag bases: m-tile t -> 16-row tile g = w*4+t ---
    const bf16* aBase[4];
#pragma unroll
    for (int t = 0; t < 4; ++t)
        aBase[t] = Vq + ((size_t)(w * 4 + t) * 24) * 512 + lane * 8;

    // --- B staging: chunk c = q*256+tid -> row = c>>3 (0..63), kp = c&7 ---
    const float* gB[2];
    int bwoff[2];
#pragma unroll
    for (int q = 0; q < 2; ++q) {
        int c = q * 256 + tid;
        int row = c >> 3, kp = c & 7;
        gB[q] = T + (size_t)(jt * MTOK + nh * 64 + row) * DDIM + kp * 8;
        bwoff[q] = (kp >> 2) * 4096 + row * 64 + ((kp & 3) << 4);
    }
    const int brd = l15 * 64 + quad * 16;   // B frag read lane offset

    f32x4 acc[4][4] = {};

    auto cvt_store = [&](float4 a, float4 b, int q, int bufo) {
        bf16x8 o;
        o[0] = (bf16)a.x; o[1] = (bf16)a.y; o[2] = (bf16)a.z; o[3] = (bf16)a.w;
        o[4] = (bf16)b.x; o[5] = (bf16)b.y; o[6] = (bf16)b.z; o[7] = (bf16)b.w;
        *(bf16x8*)(ldsB + bufo + bwoff[q]) = o;
    };

    // prologue: slabs 0,1 -> buf0; slabs 2,3 -> regs; A hs=0,1 -> regs
    float4 breg[2][2][2];
#pragma unroll
    for (int q = 0; q < 2; ++q)
#pragma unroll
        for (int s = 0; s < 2; ++s) {
            const float* p = gB[q] + s * 64;
            float4 r0 = *(const float4*)(p);
            float4 r1 = *(const float4*)(p + 4);
            cvt_store(r0, r1, q, s * 8192);
            breg[q][s][0] = *(const float4*)(p + 128);      // slab s+2
            breg[q][s][1] = *(const float4*)(p + 128 + 4);
        }
    bf16x8 apre[2][4];
#pragma unroll
    for (int hp = 0; hp < 2; ++hp)
#pragma unroll
        for (int t = 0; t < 4; ++t)
            apre[hp][t] = *(const bf16x8*)(aBase[t] + (size_t)hp * 512);
    __syncthreads();

    for (int kk = 0; kk < 6; ++kk) {
        const int buf  = (kk & 1) * 16384;
        const int nbuf = buf ^ 16384;
        if (kk < 5) {                        // stage slabs 2kk+2,2kk+3 (regs -> LDS)
#pragma unroll
            for (int q = 0; q < 2; ++q)
#pragma unroll
                for (int s = 0; s < 2; ++s)
                    cvt_store(breg[q][s][0], breg[q][s][1], q, nbuf + s * 8192);
        }
        if (kk < 4) {                        // fetch slabs 2kk+4,2kk+5 -> regs
#pragma unroll
            for (int q = 0; q < 2; ++q)
#pragma unroll
                for (int s = 0; s < 2; ++s) {
                    const float* p = gB[q] + (2 * kk + 4 + s) * 64;
                    breg[q][s][0] = *(const float4*)(p);
                    breg[q][s][1] = *(const float4*)(p + 4);
                }
        }
#pragma unroll
        for (int h = 0; h < 4; ++h) {        // 4 h-steps of K=32
            const int hs = kk * 4 + h;
            bf16x8 af[4], bb[4];
#pragma unroll
            for (int t = 0; t < 4; ++t) af[t] = apre[h & 1][t];
            if (hs + 2 < 24) {               // depth-2 A prefetch
#pragma unroll
                for (int t = 0; t < 4; ++t)
                    apre[h & 1][t] = *(const bf16x8*)(aBase[t] + (size_t)(hs + 2) * 512);
            }
            const int hb = buf + (h >> 1) * 8192 + (h & 1) * 4096;
#pragma unroll
            for (int tc = 0; tc < 4; ++tc)
                bb[tc] = *(const bf16x8*)(ldsB + hb + tc * 1024 + brd);
#pragma unroll
            for (int tr = 0; tr < 4; ++tr)
#pragma unroll
                for (int tc = 0; tc < 4; ++tc)
                    acc[tr][tc] = __builtin_amdgcn_mfma_f32_16x16x32_bf16(
                        af[tr], bb[tc], acc[tr][tc], 0, 0, 0);
        }
        __syncthreads();   // prev readers of nbuf done; buf writes visible
    }

    // epilogue: max over this half's 64 tokens (cols = tc*16 + l15)
    // C/D layout: col = lane&15, row = quad*4 + reg   [m89/m91]
#pragma unroll
    for (int tr = 0; tr < 4; ++tr) {
#pragma unroll
        for (int r = 0; r < 4; ++r) {
            float v = fmaxf(fmaxf(acc[tr][0][r], acc[tr][1][r]),
                            fmaxf(acc[tr][2][r], acc[tr][3][r]));
            v = fmaxf(v, __shfl_xor(v, 1, 64));
            v = fmaxf(v, __shfl_xor(v, 2, 64));
            v = fmaxf(v, __shfl_xor(v, 4, 64));
            v = fmaxf(v, __shfl_xor(v, 8, 64));
            if (l15 == 0)
                smax[w * 64 + tr * 16 + quad * 4 + r] = v;
        }
    }
    __syncthreads();
    Sp[((size_t)nh * BATCH + jt) * BATCH + tid] = smax[tid] * INV_TEMP;
}

// ============================================================
// CE (fused): block t computes
//   partial[t] = 0.5*(lse_j S[t][j] + lse_i S[i][t]) - S[t][t]
// where S[i][j] = max(Sp[0][j][i], Sp[1][j][i]).
// Last-arriving block reduces the 256 partials -> out (saves a launch).
// ============================================================
__global__ __launch_bounds__(64) void ce_kernel(
        const float* __restrict__ Sp, float* __restrict__ partial,
        unsigned int* __restrict__ counter, float* __restrict__ out) {
    const int t = blockIdx.x;
    const int l = threadIdx.x;
    const float* Sp0 = Sp;
    const float* Sp1 = Sp + BATCH * BATCH;

    float vr[4], vc[4];
#pragma unroll
    for (int p = 0; p < 4; ++p) {
        int j = p * 64 + l;
        vr[p] = fmaxf(Sp0[j * BATCH + t], Sp1[j * BATCH + t]);  // S[t][j]
        vc[p] = fmaxf(Sp0[t * BATCH + j], Sp1[t * BATCH + j]);  // S[j][t]
    }
    float mr = fmaxf(fmaxf(vr[0], vr[1]), fmaxf(vr[2], vr[3]));
    float mc = fmaxf(fmaxf(vc[0], vc[1]), fmaxf(vc[2], vc[3]));
    for (int o = 32; o > 0; o >>= 1) {
        mr = fmaxf(mr, __shfl_xor(mr, o, 64));
        mc = fmaxf(mc, __shfl_xor(mc, o, 64));
    }
    float sr = 0.f, sc = 0.f;
#pragma unroll
    for (int p = 0; p < 4; ++p) {
        sr += expf(vr[p] - mr);
        sc += expf(vc[p] - mc);
    }
    for (int o = 32; o > 0; o >>= 1) {
        sr += __shfl_xor(sr, o, 64);
        sc += __shfl_xor(sc, o, 64);
    }
    __shared__ int isLast;
    if (l == 0) {
        float diag = fmaxf(Sp0[t * BATCH + t], Sp1[t * BATCH + t]);
        partial[t] = 0.5f * ((mr + logf(sr)) + (mc + logf(sc))) - diag;
        __threadfence();                       // release partial[t]
        unsigned int old = atomicAdd(counter, 1u);   // device-scope [G12]
        isLast = (old == (unsigned int)(BATCH - 1));
    }
    __syncthreads();
    if (isLast) {
        __threadfence();                       // acquire all partial[]
        float s = partial[l] + partial[l + 64] + partial[l + 128] + partial[l + 192];
        for (int o = 32; o > 0; o >>= 1) s += __shfl_xor(s, o, 64);
        if (l == 0) out[0] = s / (float)BATCH;
    }
}

// ============================================================
extern "C" void kernel_launch(void* const* d_in, const int* in_sizes, int n_in,
                              void* d_out, int out_size, void* d_ws, size_t ws_size,
                              hipStream_t stream) {
    const float* v = (const float*)d_in[0];   // [256][768] fp32
    const float* T = (const float*)d_in[1];   // [256][128][768] fp32

    // ws: [ Vq bf16 NV | Sp f32 2*256*256 | partial f32 256 | counter u32 ]
    bf16*  Vq = (bf16*)d_ws;
    float* Sp = (float*)((char*)d_ws + (size_t)NV * sizeof(bf16));
    float* partial = Sp + 2 * BATCH * BATCH;
    unsigned int* counter = (unsigned int*)(partial + BATCH);

    pack_v_kernel<<<96, 256, 0, stream>>>(v, (bf16x8*)Vq, counter);
    gemm_max_kernel<<<512, 256, 0, stream>>>(Vq, T, Sp);
    ce_kernel<<<256, 64, 0, stream>>>(Sp, partial, counter, (float*)d_out);
}